// Round 1
// baseline (6098.902 us; speedup 1.0000x reference)
//
#include <hip/hip_runtime.h>
#include <hip/hip_bf16.h>
#include <math.h>

typedef __hip_bfloat16 bf16;

#define HH 56
#define WW 56
#define WSZ 7
#define SSH 3
#define NHEAD 12
#define CDIM 384
#define BBATCH 32
#define NTOK 49
#define NWIN 64
#define HIDD 1536
#define HD 32
#define NWTOT (BBATCH*NWIN)       /* 2048 windows total */
#define MROWS (NWTOT*NTOK)        /* 100352 rows */
#define LTOT (HH*WW)              /* 3136 tokens per image */
#define EPSLN 1e-5f
#define QSCALE 0.17677669529663687f

enum { M_QKV = 0, M_PROJ = 1, M_FC1 = 2, M_FC2 = 3 };

// ---------------------------------------------------------------------------
// Shared tiled GEMM: C[M x N] = A[M x K] * W^T (W is [N][K] row-major) + bias
// 64x64 tile, K-tile 32, 256 threads, 4x4 micro-tile, fp32 accumulate.
// MODE selects the A loader (fp32 gather / fp32 linear / bf16 linear) and the
// fused epilogue (scatter layouts, q-scale, gelu).
// ---------------------------------------------------------------------------
template<int MODE, int KDIM>
__global__ __launch_bounds__(256)
void gemm_k(const void* __restrict__ Ap, const float* __restrict__ Wt,
            const float* __restrict__ bias, void* __restrict__ Outp)
{
    __shared__ float As[32][68];
    __shared__ float Bs[32][68];
    const int tid = threadIdx.x;
    const int m0 = blockIdx.x * 64;
    const int n0 = blockIdx.y * 64;
    const int tx = tid & 15, ty = tid >> 4;
    const int kl = tid & 31;      // k within K-tile for staging loads
    const int rl8 = tid >> 5;     // row sub-index (0..7) for staging loads

    // Per-thread A row base offsets (8 rows, fixed across K-steps)
    long abase[8];
#pragma unroll
    for (int e = 0; e < 8; ++e) {
        int rr = m0 + e * 8 + rl8;
        if (MODE == M_QKV) {
            // fused cyclic shift + window partition gather from x[b][l][c]
            int w = rr / 49, ti = rr % 49;
            int b = w >> 6, wi = w & 63;
            int hy = (wi >> 3) * 7 + ti / 7;
            int hx = (wi & 7) * 7 + ti % 7;
            int sh = hy + SSH; if (sh >= HH) sh -= HH;
            int sw = hx + SSH; if (sw >= WW) sw -= WW;
            abase[e] = ((long)b * LTOT + sh * WW + sw) * CDIM;
        } else if (MODE == M_FC2) {
            abase[e] = (long)rr * HIDD;
        } else {
            abase[e] = (long)rr * CDIM;
        }
    }

    float acc[4][4] = {};
    const float* Af = (const float*)Ap;
    const bf16*  Ab = (const bf16*)Ap;

    for (int kt = 0; kt < KDIM; kt += 32) {
        float a_r[8], b_r[8];
#pragma unroll
        for (int e = 0; e < 8; ++e) {
            if (MODE == M_PROJ || MODE == M_FC2)
                a_r[e] = __bfloat162float(Ab[abase[e] + kt + kl]);
            else
                a_r[e] = Af[abase[e] + kt + kl];
            b_r[e] = Wt[(long)(n0 + e * 8 + rl8) * KDIM + kt + kl];
        }
        __syncthreads();   // previous tile's compute done
#pragma unroll
        for (int e = 0; e < 8; ++e) {
            As[kl][e * 8 + rl8] = a_r[e];
            Bs[kl][e * 8 + rl8] = b_r[e];
        }
        __syncthreads();
#pragma unroll
        for (int k = 0; k < 32; ++k) {
            float4 av = *(const float4*)&As[k][ty * 4];
            float4 bv = *(const float4*)&Bs[k][tx * 4];
            float aa[4] = {av.x, av.y, av.z, av.w};
            float bb[4] = {bv.x, bv.y, bv.z, bv.w};
#pragma unroll
            for (int i = 0; i < 4; ++i)
#pragma unroll
                for (int j = 0; j < 4; ++j)
                    acc[i][j] = fmaf(aa[i], bb[j], acc[i][j]);
        }
    }

    // epilogue
#pragma unroll
    for (int i = 0; i < 4; ++i) {
        int rr = m0 + ty * 4 + i;
#pragma unroll
        for (int j = 0; j < 4; ++j) {
            int n = n0 + tx * 4 + j;
            float v = acc[i][j] + bias[n];
            if (MODE == M_QKV) {
                if (n < CDIM) v *= QSCALE;              // q rows scaled
                int which = n / CDIM, nn = n % CDIM;
                int head = nn >> 5, d = nn & 31;
                int w = rr / 49, ti = rr % 49;
                ((bf16*)Outp)[((((long)w * 3 + which) * NHEAD + head) * NTOK + ti) * HD + d] =
                    __float2bfloat16(v);
            } else if (MODE == M_PROJ) {
                // fused window reverse + roll back: window coord -> final (b,l)
                int w = rr / 49, ti = rr % 49;
                int b = w >> 6, wi = w & 63;
                int hy = (wi >> 3) * 7 + ti / 7;
                int hx = (wi & 7) * 7 + ti % 7;
                int dh = hy + SSH; if (dh >= HH) dh -= HH;
                int dw = hx + SSH; if (dw >= WW) dw -= WW;
                ((bf16*)Outp)[((long)b * LTOT + dh * WW + dw) * CDIM + n] = __float2bfloat16(v);
            } else if (MODE == M_FC1) {
                float g = 0.5f * v * (1.0f + erff(v * 0.70710678118654752f)); // exact gelu
                ((bf16*)Outp)[(long)rr * HIDD + n] = __float2bfloat16(g);
            } else {
                ((bf16*)Outp)[(long)rr * CDIM + n] = __float2bfloat16(v);
            }
        }
    }
}

// ---------------------------------------------------------------------------
// Attention: one block per (window, head). q,k,v staged in LDS (pad 33),
// S in LDS (pad 50). Wave-parallel softmax over rows.
// ---------------------------------------------------------------------------
__global__ __launch_bounds__(256)
void attn_k(const bf16* __restrict__ qkv, const float* __restrict__ rpb,
            const int* __restrict__ relidx, const float* __restrict__ mask,
            bf16* __restrict__ attn_out)
{
    __shared__ float qs[49 * 33], ks[49 * 33], vs[49 * 33], Ss[49 * 50];
    const int w = blockIdx.x, head = blockIdx.y;
    const int wi = w & 63;
    const int tid = threadIdx.x;
    const bf16* qb = qkv + (((long)w * 3 + 0) * NHEAD + head) * (NTOK * HD);
    const bf16* kb = qkv + (((long)w * 3 + 1) * NHEAD + head) * (NTOK * HD);
    const bf16* vb = qkv + (((long)w * 3 + 2) * NHEAD + head) * (NTOK * HD);

    for (int i = tid; i < NTOK * HD; i += 256) {
        int n = i >> 5, d = i & 31;
        qs[n * 33 + d] = __bfloat162float(qb[i]);
        ks[n * 33 + d] = __bfloat162float(kb[i]);
        vs[n * 33 + d] = __bfloat162float(vb[i]);
    }
    __syncthreads();

    for (int idx = tid; idx < NTOK * NTOK; idx += 256) {
        int n = idx / 49, m = idx % 49;
        float dot = 0.f;
#pragma unroll
        for (int d = 0; d < HD; ++d) dot = fmaf(qs[n * 33 + d], ks[m * 33 + d], dot);
        dot += rpb[relidx[idx] * NHEAD + head];
        dot += mask[((long)wi * 49 + n) * 49 + m];
        Ss[n * 50 + m] = dot;
    }
    __syncthreads();

    const int lane = tid & 63, wv = tid >> 6;
    for (int r = wv; r < 49; r += 4) {
        float sv = (lane < 49) ? Ss[r * 50 + lane] : -1e30f;
        float mx = sv;
#pragma unroll
        for (int o = 32; o; o >>= 1) mx = fmaxf(mx, __shfl_xor(mx, o));
        float e = (lane < 49) ? expf(sv - mx) : 0.f;
        float sm = e;
#pragma unroll
        for (int o = 32; o; o >>= 1) sm += __shfl_xor(sm, o);
        if (lane < 49) Ss[r * 50 + lane] = e / sm;
    }
    __syncthreads();

    for (int idx = tid; idx < NTOK * HD; idx += 256) {
        int n = idx >> 5, d = idx & 31;
        float o = 0.f;
#pragma unroll
        for (int m = 0; m < 49; ++m) o = fmaf(Ss[n * 50 + m], vs[m * 33 + d], o);
        attn_out[((long)w * 49 + n) * CDIM + head * HD + d] = __float2bfloat16(o);
    }
}

// ---------------------------------------------------------------------------
// out[t][c] = base[t][c] + LayerNorm(Yrow[t])[c]*g + b    (one wave per token)
// base/outp may alias element-wise (LN2 in-place on d_out).
// ---------------------------------------------------------------------------
__global__ __launch_bounds__(256)
void ln_add_k(const bf16* __restrict__ Yrow, const float* base,
              const float* __restrict__ g, const float* __restrict__ bta,
              float* outp)
{
    const int wv = threadIdx.x >> 6, lane = threadIdx.x & 63;
    const long t = (long)blockIdx.x * 4 + wv;
    const bf16* yr = Yrow + t * CDIM;
    float vals[6];
    float s = 0.f;
#pragma unroll
    for (int i = 0; i < 6; ++i) { vals[i] = __bfloat162float(yr[lane + i * 64]); s += vals[i]; }
#pragma unroll
    for (int o = 32; o; o >>= 1) s += __shfl_xor(s, o);
    const float mean = s * (1.f / 384.f);
    float vsum = 0.f;
#pragma unroll
    for (int i = 0; i < 6; ++i) { float d = vals[i] - mean; vsum += d * d; }
#pragma unroll
    for (int o = 32; o; o >>= 1) vsum += __shfl_xor(vsum, o);
    const float rstd = rsqrtf(vsum * (1.f / 384.f) + EPSLN);
#pragma unroll
    for (int i = 0; i < 6; ++i) {
        int c = lane + i * 64;
        outp[t * CDIM + c] = base[t * CDIM + c] + (vals[i] - mean) * rstd * g[c] + bta[c];
    }
}

extern "C" void kernel_launch(void* const* d_in, const int* in_sizes, int n_in,
                              void* d_out, int out_size, void* d_ws, size_t ws_size,
                              hipStream_t stream)
{
    const float* x      = (const float*)d_in[0];
    const float* qkv_w  = (const float*)d_in[1];
    const float* qkv_b  = (const float*)d_in[2];
    const float* proj_w = (const float*)d_in[3];
    const float* proj_b = (const float*)d_in[4];
    const float* rpb    = (const float*)d_in[5];
    const float* ln1_g  = (const float*)d_in[6];
    const float* ln1_b  = (const float*)d_in[7];
    const float* fc1_w  = (const float*)d_in[8];
    const float* fc1_b  = (const float*)d_in[9];
    const float* fc2_w  = (const float*)d_in[10];
    const float* fc2_b  = (const float*)d_in[11];
    const float* ln2_g  = (const float*)d_in[12];
    const float* ln2_b  = (const float*)d_in[13];
    const float* amask  = (const float*)d_in[14];
    const int*   relidx = (const int*)d_in[15];
    float* out = (float*)d_out;
    char*  ws  = (char*)d_ws;

    // workspace layout (peak 385,351,680 B):
    //  [0, 231211008)            qkv bf16 [2048][3][12][49][32]   -- dead after attn
    //  [231211008, 308281344)    attn_out bf16 [100352][384]      -- dead after proj
    //  [308281344, 385351680)    P bf16 [B][L][384], later y bf16 -- P dead after LN1
    //  [0, 308281344)            H1 bf16 [100352][1536] (reuses qkv+attn_out)
    bf16* qkvb   = (bf16*)ws;
    bf16* attn_o = (bf16*)(ws + 231211008L);
    bf16* Pbuf   = (bf16*)(ws + 308281344L);
    bf16* H1     = (bf16*)ws;
    bf16* Ybuf   = Pbuf;

    dim3 blk(256);

    // 1. QKV projection (fused shift+window gather), q scaled
    gemm_k<M_QKV, CDIM><<<dim3(MROWS / 64, (3 * CDIM) / 64), blk, 0, stream>>>(
        (const void*)x, qkv_w, qkv_b, (void*)qkvb);

    // 2. windowed attention with relative position bias + shift mask
    attn_k<<<dim3(NWTOT, NHEAD), blk, 0, stream>>>(qkvb, rpb, relidx, amask, attn_o);

    // 3. output projection (fused window-reverse + roll-back scatter)
    gemm_k<M_PROJ, CDIM><<<dim3(MROWS / 64, CDIM / 64), blk, 0, stream>>>(
        (const void*)attn_o, proj_w, proj_b, (void*)Pbuf);

    // 4. x1 = x + LN1(P)  -> d_out (fp32, reused as scratch for x1)
    ln_add_k<<<dim3(MROWS / 4), blk, 0, stream>>>(Pbuf, x, ln1_g, ln1_b, out);

    // 5. H1 = gelu(x1 @ fc1^T + b)
    gemm_k<M_FC1, CDIM><<<dim3(MROWS / 64, HIDD / 64), blk, 0, stream>>>(
        (const void*)out, fc1_w, fc1_b, (void*)H1);

    // 6. y = H1 @ fc2^T + b
    gemm_k<M_FC2, HIDD><<<dim3(MROWS / 64, CDIM / 64), blk, 0, stream>>>(
        (const void*)H1, fc2_w, fc2_b, (void*)Ybuf);

    // 7. out = x1 + LN2(y)   (in-place on d_out)
    ln_add_k<<<dim3(MROWS / 4), blk, 0, stream>>>(Ybuf, out, ln2_g, ln2_b, out);
}

// Round 2
// 1580.115 us; speedup vs baseline: 3.8598x; 3.8598x over previous
//
#include <hip/hip_runtime.h>
#include <hip/hip_bf16.h>
#include <math.h>

typedef __hip_bfloat16 bf16;
typedef __bf16 bf16x8 __attribute__((ext_vector_type(8)));
typedef float f32x4 __attribute__((ext_vector_type(4)));

#define HH 56
#define WW 56
#define WSZ 7
#define SSH 3
#define NHEAD 12
#define CDIM 384
#define BBATCH 32
#define NTOK 49
#define NWIN 64
#define HIDD 1536
#define HD 32
#define NWTOT (BBATCH*NWIN)       /* 2048 windows */
#define MROWS (NWTOT*NTOK)        /* 100352 rows */
#define MHALF (MROWS/2)           /* 50176 */
#define LTOT (HH*WW)
#define EPSLN 1e-5f
#define QSCALE 0.17677669529663687f

enum { M_QKV = 0, M_PROJ = 1, M_FC1 = 2, M_FC2 = 3 };

__device__ __forceinline__ void gload16(const void* g, void* l) {
    __builtin_amdgcn_global_load_lds(
        (const __attribute__((address_space(1))) void*)g,
        (__attribute__((address_space(3))) void*)l, 16, 0, 0);
}

// ---------------------------------------------------------------------------
// fp32 -> bf16 convert (weights)
// ---------------------------------------------------------------------------
__global__ __launch_bounds__(256) void cvt_k(const float* __restrict__ src,
                                             bf16* __restrict__ dst, int n) {
    int i = blockIdx.x * 256 + threadIdx.x;
    if (i < n) dst[i] = __float2bfloat16(src[i]);
}

// ---------------------------------------------------------------------------
// x [B][L][C] fp32 -> xw [MROWS][C] bf16 with cyclic shift + window partition
// ---------------------------------------------------------------------------
__global__ __launch_bounds__(256) void gather_k(const float* __restrict__ x,
                                                bf16* __restrict__ xw) {
    int idx = blockIdx.x * 256 + threadIdx.x;      // MROWS*96 threads, 4 c each
    int rr = idx / 96, c4 = (idx % 96) * 4;
    int w = rr / 49, ti = rr % 49;
    int b = w >> 6, wi = w & 63;
    int hy = (wi >> 3) * 7 + ti / 7;
    int hx = (wi & 7) * 7 + ti % 7;
    int sh = hy + SSH; if (sh >= HH) sh -= HH;
    int sw = hx + SSH; if (sw >= WW) sw -= WW;
    float4 v = *(const float4*)&x[((long)b * LTOT + sh * WW + sw) * CDIM + c4];
    bf16* o = &xw[(long)rr * CDIM + c4];
    o[0] = __float2bfloat16(v.x); o[1] = __float2bfloat16(v.y);
    o[2] = __float2bfloat16(v.z); o[3] = __float2bfloat16(v.w);
}

// ---------------------------------------------------------------------------
// MFMA GEMM: C[M x N] = A[M x K](bf16) * W^T (W [N][K] bf16) + bias, fused
// epilogue per MODE. 128x128 tile, BK=64, 256 thr = 4 waves (2x2), each wave
// 64x64 = 4x4 fragments of 16x16x32. global_load_lds(16B) staging, linear LDS.
// ---------------------------------------------------------------------------
template<int MODE, int KDIM>
__global__ __launch_bounds__(256)
void mgemm_k(const bf16* __restrict__ A, const bf16* __restrict__ Wt,
             const float* __restrict__ bias, void* __restrict__ Outp)
{
    __shared__ bf16 As[128 * 64];
    __shared__ bf16 Bs[128 * 64];
    const int tid = threadIdx.x;
    const int wid = tid >> 6, lane = tid & 63;
    const int m0 = blockIdx.x * 128;
    const int n0 = blockIdx.y * 128;

    // staging: wave wid covers rows [wid*32, wid*32+32) in 4 issues of 8 rows
    const int srow = lane >> 3, sseg = lane & 7;
    const bf16* Ag = A + (long)(m0 + wid * 32 + srow) * KDIM + sseg * 8;
    const bf16* Wg = Wt + (long)(n0 + wid * 32 + srow) * KDIM + sseg * 8;
    bf16* AsW = &As[(wid * 32) * 64];
    bf16* BsW = &Bs[(wid * 32) * 64];

    const int wr = (wid >> 1) * 64, wc = (wid & 1) * 64;
    const int frow = lane & 15, fk = (lane >> 4) * 8;

    f32x4 acc[4][4] = {};

    for (int kt = 0; kt < KDIM; kt += 64) {
#pragma unroll
        for (int i = 0; i < 4; ++i) {
            gload16(Ag + (long)(i * 8) * KDIM + kt, AsW + i * 512);
            gload16(Wg + (long)(i * 8) * KDIM + kt, BsW + i * 512);
        }
        __syncthreads();   // drain DMA, publish tile
#pragma unroll
        for (int kk = 0; kk < 2; ++kk) {
            bf16x8 af[4], bfr[4];
#pragma unroll
            for (int i = 0; i < 4; ++i) {
                af[i]  = *(const bf16x8*)&As[(wr + i * 16 + frow) * 64 + kk * 32 + fk];
                bfr[i] = *(const bf16x8*)&Bs[(wc + i * 16 + frow) * 64 + kk * 32 + fk];
            }
#pragma unroll
            for (int mi = 0; mi < 4; ++mi)
#pragma unroll
                for (int ni = 0; ni < 4; ++ni)
                    acc[mi][ni] = __builtin_amdgcn_mfma_f32_16x16x32_bf16(
                        af[mi], bfr[ni], acc[mi][ni], 0, 0, 0);
        }
        __syncthreads();   // protect LDS before next overwrite
    }

    // epilogue: D col = lane&15, row = (lane>>4)*4 + j
#pragma unroll
    for (int mi = 0; mi < 4; ++mi) {
#pragma unroll
        for (int ni = 0; ni < 4; ++ni) {
            const int n = n0 + wc + ni * 16 + frow;
            const float bn = bias[n];
#pragma unroll
            for (int j = 0; j < 4; ++j) {
                const int m = m0 + wr + mi * 16 + (lane >> 4) * 4 + j;
                float v = acc[mi][ni][j] + bn;
                if (MODE == M_QKV) {
                    if (n < CDIM) v *= QSCALE;
                    int which = n / CDIM, nn = n % CDIM;
                    int head = nn >> 5, d = nn & 31;
                    int w = m / 49, ti = m % 49;
                    ((bf16*)Outp)[((((long)w * 3 + which) * NHEAD + head) * NTOK + ti) * HD + d]
                        = __float2bfloat16(v);
                } else if (MODE == M_PROJ) {
                    int w = m / 49, ti = m % 49;
                    int b = w >> 6, wi = w & 63;
                    int hy = (wi >> 3) * 7 + ti / 7;
                    int hx = (wi & 7) * 7 + ti % 7;
                    int dh = hy + SSH; if (dh >= HH) dh -= HH;
                    int dw = hx + SSH; if (dw >= WW) dw -= WW;
                    ((bf16*)Outp)[((long)b * LTOT + dh * WW + dw) * CDIM + n]
                        = __float2bfloat16(v);
                } else if (MODE == M_FC1) {
                    float g = 0.5f * v * (1.0f + erff(v * 0.70710678118654752f));
                    ((bf16*)Outp)[(long)m * HIDD + n] = __float2bfloat16(g);
                } else {
                    ((bf16*)Outp)[(long)m * CDIM + n] = __float2bfloat16(v);
                }
            }
        }
    }
}

// ---------------------------------------------------------------------------
// Attention: one block per (window, head). Scalar VALU version (round 2).
// ---------------------------------------------------------------------------
__global__ __launch_bounds__(256)
void attn_k(const bf16* __restrict__ qkv, const float* __restrict__ rpb,
            const int* __restrict__ relidx, const float* __restrict__ mask,
            bf16* __restrict__ attn_out)
{
    __shared__ float qs[49 * 33], ks[49 * 33], vs[49 * 33], Ss[49 * 50];
    const int w = blockIdx.x, head = blockIdx.y;
    const int wi = w & 63;
    const int tid = threadIdx.x;
    const bf16* qb = qkv + (((long)w * 3 + 0) * NHEAD + head) * (NTOK * HD);
    const bf16* kb = qkv + (((long)w * 3 + 1) * NHEAD + head) * (NTOK * HD);
    const bf16* vb = qkv + (((long)w * 3 + 2) * NHEAD + head) * (NTOK * HD);

    for (int i = tid; i < NTOK * HD; i += 256) {
        int n = i >> 5, d = i & 31;
        qs[n * 33 + d] = __bfloat162float(qb[i]);
        ks[n * 33 + d] = __bfloat162float(kb[i]);
        vs[n * 33 + d] = __bfloat162float(vb[i]);
    }
    __syncthreads();

    for (int idx = tid; idx < NTOK * NTOK; idx += 256) {
        int n = idx / 49, m = idx % 49;
        float dot = 0.f;
#pragma unroll
        for (int d = 0; d < HD; ++d) dot = fmaf(qs[n * 33 + d], ks[m * 33 + d], dot);
        dot += rpb[relidx[idx] * NHEAD + head];
        dot += mask[((long)wi * 49 + n) * 49 + m];
        Ss[n * 50 + m] = dot;
    }
    __syncthreads();

    const int lane = tid & 63, wv = tid >> 6;
    for (int r = wv; r < 49; r += 4) {
        float sv = (lane < 49) ? Ss[r * 50 + lane] : -1e30f;
        float mx = sv;
#pragma unroll
        for (int o = 32; o; o >>= 1) mx = fmaxf(mx, __shfl_xor(mx, o));
        float e = (lane < 49) ? expf(sv - mx) : 0.f;
        float sm = e;
#pragma unroll
        for (int o = 32; o; o >>= 1) sm += __shfl_xor(sm, o);
        if (lane < 49) Ss[r * 50 + lane] = e / sm;
    }
    __syncthreads();

    for (int idx = tid; idx < NTOK * HD; idx += 256) {
        int n = idx >> 5, d = idx & 31;
        float o = 0.f;
#pragma unroll
        for (int m = 0; m < 49; ++m) o = fmaf(Ss[n * 50 + m], vs[m * 33 + d], o);
        attn_out[((long)w * 49 + n) * CDIM + head * HD + d] = __float2bfloat16(o);
    }
}

// ---------------------------------------------------------------------------
// out[t] = base[t] + LN(Yrow[t])*g + b ; optionally also write bf16 copy of out
// ---------------------------------------------------------------------------
__global__ __launch_bounds__(256)
void ln_add_k(const bf16* __restrict__ Yrow, const float* base,
              const float* __restrict__ g, const float* __restrict__ bta,
              float* outp, bf16* outb)
{
    const int wv = threadIdx.x >> 6, lane = threadIdx.x & 63;
    const long t = (long)blockIdx.x * 4 + wv;
    const bf16* yr = Yrow + t * CDIM;
    float vals[6];
    float s = 0.f;
#pragma unroll
    for (int i = 0; i < 6; ++i) { vals[i] = __bfloat162float(yr[lane + i * 64]); s += vals[i]; }
#pragma unroll
    for (int o = 32; o; o >>= 1) s += __shfl_xor(s, o);
    const float mean = s * (1.f / 384.f);
    float vsum = 0.f;
#pragma unroll
    for (int i = 0; i < 6; ++i) { float d = vals[i] - mean; vsum += d * d; }
#pragma unroll
    for (int o = 32; o; o >>= 1) vsum += __shfl_xor(vsum, o);
    const float rstd = rsqrtf(vsum * (1.f / 384.f) + EPSLN);
#pragma unroll
    for (int i = 0; i < 6; ++i) {
        int c = lane + i * 64;
        float r = base[t * CDIM + c] + (vals[i] - mean) * rstd * g[c] + bta[c];
        outp[t * CDIM + c] = r;
        if (outb) outb[t * CDIM + c] = __float2bfloat16(r);
    }
}

extern "C" void kernel_launch(void* const* d_in, const int* in_sizes, int n_in,
                              void* d_out, int out_size, void* d_ws, size_t ws_size,
                              hipStream_t stream)
{
    const float* x      = (const float*)d_in[0];
    const float* qkv_w  = (const float*)d_in[1];
    const float* qkv_b  = (const float*)d_in[2];
    const float* proj_w = (const float*)d_in[3];
    const float* proj_b = (const float*)d_in[4];
    const float* rpb    = (const float*)d_in[5];
    const float* ln1_g  = (const float*)d_in[6];
    const float* ln1_b  = (const float*)d_in[7];
    const float* fc1_w  = (const float*)d_in[8];
    const float* fc1_b  = (const float*)d_in[9];
    const float* fc2_w  = (const float*)d_in[10];
    const float* fc2_b  = (const float*)d_in[11];
    const float* ln2_g  = (const float*)d_in[12];
    const float* ln2_b  = (const float*)d_in[13];
    const float* amask  = (const float*)d_in[14];
    const int*   relidx = (const int*)d_in[15];
    float* out = (float*)d_out;
    char*  ws  = (char*)d_ws;

    // workspace layout (peak 311,820,288 B)
    bf16* wq  = (bf16*)(ws + 0L);           //   884,736  qkv_w bf16
    bf16* wp  = (bf16*)(ws + 884736L);      //   294,912  proj_w bf16
    bf16* w1  = (bf16*)(ws + 1179648L);     // 1,179,648  fc1_w bf16
    bf16* w2  = (bf16*)(ws + 2359296L);     // 1,179,648  fc2_w bf16
    bf16* xw     = (bf16*)(ws + 3538944L);      // 77,070,336  (dead after QKV)
    bf16* qkvb   = (bf16*)(ws + 80609280L);     // 231,211,008 (dead after attn)
    bf16* attn_o = (bf16*)(ws + 3538944L);      // 77,070,336  (reuses xw; dead after proj)
    bf16* Pbuf   = (bf16*)(ws + 80609280L);     // 77,070,336  (dead after LN1)
    bf16* x1b    = (bf16*)(ws + 157679616L);    // 77,070,336  (dead after FC1)
    bf16* H1     = (bf16*)(ws + 3538944L);      // 154,140,672 half-M hidden
    bf16* Ybuf   = (bf16*)(ws + 234749952L);    // 77,070,336

    dim3 blk(256);

    // 0. weight conversion + windowed gather of x
    cvt_k<<<dim3((3*CDIM*CDIM + 255)/256), blk, 0, stream>>>(qkv_w, wq, 3*CDIM*CDIM);
    cvt_k<<<dim3((CDIM*CDIM + 255)/256), blk, 0, stream>>>(proj_w, wp, CDIM*CDIM);
    cvt_k<<<dim3((HIDD*CDIM + 255)/256), blk, 0, stream>>>(fc1_w, w1, HIDD*CDIM);
    cvt_k<<<dim3((CDIM*HIDD + 255)/256), blk, 0, stream>>>(fc2_w, w2, CDIM*HIDD);
    gather_k<<<dim3(MROWS * 96 / 256), blk, 0, stream>>>(x, xw);

    // 1. QKV projection
    mgemm_k<M_QKV, CDIM><<<dim3(MROWS/128, (3*CDIM)/128), blk, 0, stream>>>(
        xw, wq, qkv_b, (void*)qkvb);

    // 2. windowed attention
    attn_k<<<dim3(NWTOT, NHEAD), blk, 0, stream>>>(qkvb, rpb, relidx, amask, attn_o);

    // 3. output projection (fused window-reverse scatter)
    mgemm_k<M_PROJ, CDIM><<<dim3(MROWS/128, CDIM/128), blk, 0, stream>>>(
        attn_o, wp, proj_b, (void*)Pbuf);

    // 4. x1 = x + LN1(P) -> d_out fp32, + bf16 copy for FC1
    ln_add_k<<<dim3(MROWS/4), blk, 0, stream>>>(Pbuf, x, ln1_g, ln1_b, out, x1b);

    // 5/6. FFN in two M-chunks (H1-half fits workspace)
    for (int c = 0; c < 2; ++c) {
        const bf16* a1 = x1b + (long)c * MHALF * CDIM;
        bf16* yc = Ybuf + (long)c * MHALF * CDIM;
        mgemm_k<M_FC1, CDIM><<<dim3(MHALF/128, HIDD/128), blk, 0, stream>>>(
            a1, w1, fc1_b, (void*)H1);
        mgemm_k<M_FC2, HIDD><<<dim3(MHALF/128, CDIM/128), blk, 0, stream>>>(
            H1, w2, fc2_b, (void*)yc);
    }

    // 7. out = x1 + LN2(y)  (in-place)
    ln_add_k<<<dim3(MROWS/4), blk, 0, stream>>>(Ybuf, out, ln2_g, ln2_b, out, nullptr);
}

// Round 3
// 1281.755 us; speedup vs baseline: 4.7582x; 1.2328x over previous
//
#include <hip/hip_runtime.h>
#include <hip/hip_bf16.h>
#include <math.h>

typedef __hip_bfloat16 bf16;
typedef __bf16 bf16x8 __attribute__((ext_vector_type(8)));
typedef float f32x4 __attribute__((ext_vector_type(4)));

#define HH 56
#define WW 56
#define WSZ 7
#define SSH 3
#define NHEAD 12
#define CDIM 384
#define BBATCH 32
#define NTOK 49
#define NWIN 64
#define HIDD 1536
#define HD 32
#define NWTOT (BBATCH*NWIN)       /* 2048 windows */
#define MROWS (NWTOT*NTOK)        /* 100352 rows */
#define MQ (MROWS/4)              /* 25088 */
#define LTOT (HH*WW)
#define EPSLN 1e-5f
#define QSCALE 0.17677669529663687f
#define NEGBIG -1e30f

enum { M_QKV = 0, M_PROJ = 1, M_FC1 = 2, M_FC2 = 3 };

__device__ __forceinline__ void gload16(const void* g, void* l) {
    __builtin_amdgcn_global_load_lds(
        (const __attribute__((address_space(1))) void*)g,
        (__attribute__((address_space(3))) void*)l, 16, 0, 0);
}

__device__ __forceinline__ unsigned short bfbits(float v) {
    bf16 b = __float2bfloat16(v);
    return *reinterpret_cast<unsigned short*>(&b);
}

// ---------------------------------------------------------------------------
__global__ __launch_bounds__(256) void cvt_k(const float* __restrict__ src,
                                             bf16* __restrict__ dst, int n) {
    int i = blockIdx.x * 256 + threadIdx.x;
    if (i < n) dst[i] = __float2bfloat16(src[i]);
}

// bias+mask table: tbl[wi][h][n][m(pad64)] ; m>=49 -> -1e30 (softmax automask)
__global__ __launch_bounds__(256)
void tbl_k(const float* __restrict__ rpb, const int* __restrict__ relidx,
           const float* __restrict__ amask, float* __restrict__ tbl) {
    int idx = blockIdx.x * 256 + threadIdx.x;   // 64*12*64*64
    int m = idx & 63, n = (idx >> 6) & 63;
    int h = (idx >> 12) % NHEAD, wi = idx / (64 * 64 * NHEAD);
    float v;
    if (m >= NTOK) v = NEGBIG;
    else if (n >= NTOK) v = 0.f;
    else v = rpb[relidx[n * NTOK + m] * NHEAD + h] + amask[((long)wi * NTOK + n) * NTOK + m];
    tbl[idx] = v;
}

// x [B][L][C] fp32 -> xw [MROWS][C] bf16 with cyclic shift + window partition
__global__ __launch_bounds__(256) void gather_k(const float* __restrict__ x,
                                                bf16* __restrict__ xw) {
    int idx = blockIdx.x * 256 + threadIdx.x;
    int rr = idx / 96, c4 = (idx % 96) * 4;
    int w = rr / 49, ti = rr % 49;
    int b = w >> 6, wi = w & 63;
    int hy = (wi >> 3) * 7 + ti / 7;
    int hx = (wi & 7) * 7 + ti % 7;
    int sh = hy + SSH; if (sh >= HH) sh -= HH;
    int sw = hx + SSH; if (sw >= WW) sw -= WW;
    float4 v = *(const float4*)&x[((long)b * LTOT + sh * WW + sw) * CDIM + c4];
    bf16* o = &xw[(long)rr * CDIM + c4];
    o[0] = __float2bfloat16(v.x); o[1] = __float2bfloat16(v.y);
    o[2] = __float2bfloat16(v.z); o[3] = __float2bfloat16(v.w);
}

// ---------------------------------------------------------------------------
// MFMA GEMM (as round 2). M_QKV writes q,k -> Outp [w][2][h][49][32] and
// v -> Outp2 transposed [w][h][32][64pad].
// ---------------------------------------------------------------------------
template<int MODE, int KDIM>
__global__ __launch_bounds__(256)
void mgemm_k(const bf16* __restrict__ A, const bf16* __restrict__ Wt,
             const float* __restrict__ bias, void* __restrict__ Outp,
             void* __restrict__ Outp2)
{
    __shared__ bf16 As[128 * 64];
    __shared__ bf16 Bs[128 * 64];
    const int tid = threadIdx.x;
    const int wid = tid >> 6, lane = tid & 63;
    const int m0 = blockIdx.x * 128;
    const int n0 = blockIdx.y * 128;

    const int srow = lane >> 3, sseg = lane & 7;
    const bf16* Ag = A + (long)(m0 + wid * 32 + srow) * KDIM + sseg * 8;
    const bf16* Wg = Wt + (long)(n0 + wid * 32 + srow) * KDIM + sseg * 8;
    bf16* AsW = &As[(wid * 32) * 64];
    bf16* BsW = &Bs[(wid * 32) * 64];

    const int wr = (wid >> 1) * 64, wc = (wid & 1) * 64;
    const int frow = lane & 15, fk = (lane >> 4) * 8;

    f32x4 acc[4][4] = {};

    for (int kt = 0; kt < KDIM; kt += 64) {
#pragma unroll
        for (int i = 0; i < 4; ++i) {
            gload16(Ag + (long)(i * 8) * KDIM + kt, AsW + i * 512);
            gload16(Wg + (long)(i * 8) * KDIM + kt, BsW + i * 512);
        }
        __syncthreads();
#pragma unroll
        for (int kk = 0; kk < 2; ++kk) {
            bf16x8 af[4], bfr[4];
#pragma unroll
            for (int i = 0; i < 4; ++i) {
                af[i]  = *(const bf16x8*)&As[(wr + i * 16 + frow) * 64 + kk * 32 + fk];
                bfr[i] = *(const bf16x8*)&Bs[(wc + i * 16 + frow) * 64 + kk * 32 + fk];
            }
#pragma unroll
            for (int mi = 0; mi < 4; ++mi)
#pragma unroll
                for (int ni = 0; ni < 4; ++ni)
                    acc[mi][ni] = __builtin_amdgcn_mfma_f32_16x16x32_bf16(
                        af[mi], bfr[ni], acc[mi][ni], 0, 0, 0);
        }
        __syncthreads();
    }

#pragma unroll
    for (int mi = 0; mi < 4; ++mi) {
#pragma unroll
        for (int ni = 0; ni < 4; ++ni) {
            const int n = n0 + wc + ni * 16 + frow;
            const float bn = bias[n];
#pragma unroll
            for (int j = 0; j < 4; ++j) {
                const int m = m0 + wr + mi * 16 + (lane >> 4) * 4 + j;
                float v = acc[mi][ni][j] + bn;
                if (MODE == M_QKV) {
                    int which = n / CDIM, nn = n % CDIM;
                    int head = nn >> 5, d = nn & 31;
                    int w = m / 49, ti = m % 49;
                    if (which == 2) {
                        ((bf16*)Outp2)[(((long)w * NHEAD + head) * HD + d) * 64 + ti]
                            = __float2bfloat16(v);
                    } else {
                        if (which == 0) v *= QSCALE;
                        ((bf16*)Outp)[((((long)w * 2 + which) * NHEAD + head) * NTOK + ti) * HD + d]
                            = __float2bfloat16(v);
                    }
                } else if (MODE == M_PROJ) {
                    int w = m / 49, ti = m % 49;
                    int b = w >> 6, wi = w & 63;
                    int hy = (wi >> 3) * 7 + ti / 7;
                    int hx = (wi & 7) * 7 + ti % 7;
                    int dh = hy + SSH; if (dh >= HH) dh -= HH;
                    int dw = hx + SSH; if (dw >= WW) dw -= WW;
                    ((bf16*)Outp)[((long)b * LTOT + dh * WW + dw) * CDIM + n]
                        = __float2bfloat16(v);
                } else if (MODE == M_FC1) {
                    float g = 0.5f * v * (1.0f + erff(v * 0.70710678118654752f));
                    ((bf16*)Outp)[(long)m * HIDD + n] = __float2bfloat16(g);
                } else {
                    ((bf16*)Outp)[(long)m * CDIM + n] = __float2bfloat16(v);
                }
            }
        }
    }
}

// ---------------------------------------------------------------------------
// MFMA attention: 4 waves/block, each wave = one (window, head).
// S^T = mfma(K,Q) (m rows, n cols, 64x64 pad); +tbl; wave-parallel softmax
// (16 in-reg values/col + shfl_xor 16,32); P -> wave-private LDS [64][72pad];
// PV = mfma(P_lds, V^T_global). No barriers.
// ---------------------------------------------------------------------------
__global__ __launch_bounds__(256)
void mattn_k(const bf16* __restrict__ qk, const bf16* __restrict__ vT,
             const float* __restrict__ tbl, bf16* __restrict__ attn_out)
{
    __shared__ bf16 Plds[4][64 * 72];
    const int tid = threadIdx.x, wid = tid >> 6, lane = tid & 63;
    const int t = blockIdx.x * 4 + wid;
    const int w = t / NHEAD, h = t % NHEAD, wi = w & 63;
    const int l15 = lane & 15, g = lane >> 4;
    const bf16* qb = qk + ((long)(w * 2 + 0) * NHEAD + h) * (NTOK * HD);
    const bf16* kb = qk + ((long)(w * 2 + 1) * NHEAD + h) * (NTOK * HD);
    const bf16* vt = vT + ((long)w * NHEAD + h) * (HD * 64);
    const float* Tb = tbl + (long)(wi * NHEAD + h) * 64 * 64;
    char* Pw = (char*)&Plds[wid][0];

    // --- S^T = K @ Q^T (contraction over d=32, one k-step) ---
    bf16x8 kf[4], qf[4];
#pragma unroll
    for (int i = 0; i < 4; ++i) {
        kf[i] = *(const bf16x8*)&kb[(16 * i + l15) * HD + 8 * g];
        qf[i] = *(const bf16x8*)&qb[(16 * i + l15) * HD + 8 * g];
    }
    f32x4 s[4][4] = {};
#pragma unroll
    for (int mi = 0; mi < 4; ++mi)
#pragma unroll
        for (int ni = 0; ni < 4; ++ni)
            s[mi][ni] = __builtin_amdgcn_mfma_f32_16x16x32_bf16(
                kf[mi], qf[ni], s[mi][ni], 0, 0, 0);

    // --- +bias/mask table, softmax over m per column n, P -> LDS ---
#pragma unroll
    for (int ni = 0; ni < 4; ++ni) {
        const int n = 16 * ni + l15;
#pragma unroll
        for (int mi = 0; mi < 4; ++mi) {
            float4 tv = *(const float4*)&Tb[(long)n * 64 + 16 * mi + 4 * g];
            s[mi][ni][0] += tv.x; s[mi][ni][1] += tv.y;
            s[mi][ni][2] += tv.z; s[mi][ni][3] += tv.w;
        }
        float mx = NEGBIG;
#pragma unroll
        for (int mi = 0; mi < 4; ++mi)
#pragma unroll
            for (int j = 0; j < 4; ++j) mx = fmaxf(mx, s[mi][ni][j]);
        mx = fmaxf(mx, __shfl_xor(mx, 16));
        mx = fmaxf(mx, __shfl_xor(mx, 32));
        float sum = 0.f;
#pragma unroll
        for (int mi = 0; mi < 4; ++mi)
#pragma unroll
            for (int j = 0; j < 4; ++j) {
                float e = expf(s[mi][ni][j] - mx);
                s[mi][ni][j] = e; sum += e;
            }
        sum += __shfl_xor(sum, 16);
        sum += __shfl_xor(sum, 32);
        const float r = 1.0f / sum;
#pragma unroll
        for (int mi = 0; mi < 4; ++mi) {
            ushort4 u;
            u.x = bfbits(s[mi][ni][0] * r);
            u.y = bfbits(s[mi][ni][1] * r);
            u.z = bfbits(s[mi][ni][2] * r);
            u.w = bfbits(s[mi][ni][3] * r);
            *(ushort4*)(Pw + (long)n * 144 + (16 * mi + 4 * g) * 2) = u;
        }
    }

    // --- PV: out[n][d] = P @ V  (contraction over m=64, 2 k-steps) ---
    f32x4 o[4][2] = {};
#pragma unroll
    for (int kk = 0; kk < 2; ++kk) {
        bf16x8 vf[2];
        vf[0] = *(const bf16x8*)&vt[(long)(l15) * 64 + 32 * kk + 8 * g];
        vf[1] = *(const bf16x8*)&vt[(long)(16 + l15) * 64 + 32 * kk + 8 * g];
#pragma unroll
        for (int rt = 0; rt < 4; ++rt) {
            bf16x8 pf = *(const bf16x8*)(Pw + (long)(16 * rt + l15) * 144 + (32 * kk + 8 * g) * 2);
            o[rt][0] = __builtin_amdgcn_mfma_f32_16x16x32_bf16(pf, vf[0], o[rt][0], 0, 0, 0);
            o[rt][1] = __builtin_amdgcn_mfma_f32_16x16x32_bf16(pf, vf[1], o[rt][1], 0, 0, 0);
        }
    }

#pragma unroll
    for (int rt = 0; rt < 4; ++rt)
#pragma unroll
        for (int dt = 0; dt < 2; ++dt)
#pragma unroll
            for (int j = 0; j < 4; ++j) {
                int n = 16 * rt + 4 * g + j;
                if (n < NTOK)
                    attn_out[((long)w * NTOK + n) * CDIM + h * HD + 16 * dt + l15]
                        = __float2bfloat16(o[rt][dt][j]);
            }
}

// ---------------------------------------------------------------------------
__global__ __launch_bounds__(256)
void ln_add_k(const bf16* __restrict__ Yrow, const float* base,
              const float* __restrict__ g, const float* __restrict__ bta,
              float* outp, bf16* outb)
{
    const int wv = threadIdx.x >> 6, lane = threadIdx.x & 63;
    const long t = (long)blockIdx.x * 4 + wv;
    const bf16* yr = Yrow + t * CDIM;
    float vals[6];
    float s = 0.f;
#pragma unroll
    for (int i = 0; i < 6; ++i) { vals[i] = __bfloat162float(yr[lane + i * 64]); s += vals[i]; }
#pragma unroll
    for (int o = 32; o; o >>= 1) s += __shfl_xor(s, o);
    const float mean = s * (1.f / 384.f);
    float vsum = 0.f;
#pragma unroll
    for (int i = 0; i < 6; ++i) { float d = vals[i] - mean; vsum += d * d; }
#pragma unroll
    for (int o = 32; o; o >>= 1) vsum += __shfl_xor(vsum, o);
    const float rstd = rsqrtf(vsum * (1.f / 384.f) + EPSLN);
#pragma unroll
    for (int i = 0; i < 6; ++i) {
        int c = lane + i * 64;
        float r = base[t * CDIM + c] + (vals[i] - mean) * rstd * g[c] + bta[c];
        outp[t * CDIM + c] = r;
        if (outb) outb[t * CDIM + c] = __float2bfloat16(r);
    }
}

extern "C" void kernel_launch(void* const* d_in, const int* in_sizes, int n_in,
                              void* d_out, int out_size, void* d_ws, size_t ws_size,
                              hipStream_t stream)
{
    const float* x      = (const float*)d_in[0];
    const float* qkv_w  = (const float*)d_in[1];
    const float* qkv_b  = (const float*)d_in[2];
    const float* proj_w = (const float*)d_in[3];
    const float* proj_b = (const float*)d_in[4];
    const float* rpb    = (const float*)d_in[5];
    const float* ln1_g  = (const float*)d_in[6];
    const float* ln1_b  = (const float*)d_in[7];
    const float* fc1_w  = (const float*)d_in[8];
    const float* fc1_b  = (const float*)d_in[9];
    const float* fc2_w  = (const float*)d_in[10];
    const float* fc2_b  = (const float*)d_in[11];
    const float* ln2_g  = (const float*)d_in[12];
    const float* ln2_b  = (const float*)d_in[13];
    const float* amask  = (const float*)d_in[14];
    const int*   relidx = (const int*)d_in[15];
    float* out = (float*)d_out;
    char*  ws  = (char*)d_ws;

    // workspace layout (peak 347,996,160 B; 385,351,680 proven available in R1)
    bf16*  wq   = (bf16*) (ws + 0L);
    bf16*  wp   = (bf16*) (ws + 884736L);
    bf16*  w1   = (bf16*) (ws + 1179648L);
    bf16*  w2   = (bf16*) (ws + 2359296L);
    float* tbl  = (float*)(ws + 3538944L);      // 12,582,912
    bf16*  xw   = (bf16*) (ws + 16121856L);     // 77,070,336  (dead after QKV)
    bf16*  qkb  = (bf16*) (ws + 93192192L);     // 154,140,672 q,k (dead after attn)
    bf16*  vTb  = (bf16*) (ws + 247332864L);    // 100,663,296 v^T (dead after attn)
    bf16*  attn_o = (bf16*)(ws + 16121856L);    // reuses xw (dead after proj)
    bf16*  Pbuf = (bf16*) (ws + 93192192L);     // reuses qk (dead after LN1)
    bf16*  x1b  = (bf16*) (ws + 170262528L);    // reuses qk (dead after FC1s)
    bf16*  H1   = (bf16*) (ws + 247332864L);    // reuses vT (per FFN chunk)
    bf16*  Ybuf = (bf16*) (ws + 93192192L);     // reuses Pbuf (after LN1)

    dim3 blk(256);

    cvt_k<<<dim3((3*CDIM*CDIM + 255)/256), blk, 0, stream>>>(qkv_w, wq, 3*CDIM*CDIM);
    cvt_k<<<dim3((CDIM*CDIM + 255)/256), blk, 0, stream>>>(proj_w, wp, CDIM*CDIM);
    cvt_k<<<dim3((HIDD*CDIM + 255)/256), blk, 0, stream>>>(fc1_w, w1, HIDD*CDIM);
    cvt_k<<<dim3((CDIM*HIDD + 255)/256), blk, 0, stream>>>(fc2_w, w2, CDIM*HIDD);
    tbl_k<<<dim3(64*12*64*64/256), blk, 0, stream>>>(rpb, relidx, amask, tbl);
    gather_k<<<dim3(MROWS * 96 / 256), blk, 0, stream>>>(x, xw);

    // 1. QKV projection (q,k normal; v transposed)
    mgemm_k<M_QKV, CDIM><<<dim3(MROWS/128, (3*CDIM)/128), blk, 0, stream>>>(
        xw, wq, qkv_b, (void*)qkb, (void*)vTb);

    // 2. MFMA windowed attention
    mattn_k<<<dim3(NWTOT * NHEAD / 4), blk, 0, stream>>>(qkb, vTb, tbl, attn_o);

    // 3. output projection (fused window-reverse scatter)
    mgemm_k<M_PROJ, CDIM><<<dim3(MROWS/128, CDIM/128), blk, 0, stream>>>(
        attn_o, wp, proj_b, (void*)Pbuf, nullptr);

    // 4. x1 = x + LN1(P) -> d_out fp32 + bf16 copy
    ln_add_k<<<dim3(MROWS/4), blk, 0, stream>>>(Pbuf, x, ln1_g, ln1_b, out, x1b);

    // 5/6. FFN in four M-chunks (H1 chunk fits freed vT region)
    for (int c = 0; c < 4; ++c) {
        const bf16* a1 = x1b + (long)c * MQ * CDIM;
        bf16* yc = Ybuf + (long)c * MQ * CDIM;
        mgemm_k<M_FC1, CDIM><<<dim3(MQ/128, HIDD/128), blk, 0, stream>>>(
            a1, w1, fc1_b, (void*)H1, nullptr);
        mgemm_k<M_FC2, HIDD><<<dim3(MQ/128, CDIM/128), blk, 0, stream>>>(
            H1, w2, fc2_b, (void*)yc, nullptr);
    }

    // 7. out = x1 + LN2(y)  (in-place)
    ln_add_k<<<dim3(MROWS/4), blk, 0, stream>>>(Ybuf, out, ln2_g, ln2_b, out, nullptr);
}